// Round 9
// baseline (234.473 us; speedup 1.0000x reference)
//
#include <hip/hip_runtime.h>
#include <math.h>
#include <type_traits>

#define N_NODES 50000
#define N_EDGES 800000
#define DIM 96
#define BCH 6                     // 16-byte fp8 chunks per 96B row (6 lanes/row)
#define SCAN_BLK 256
#define NBLK ((N_NODES + SCAN_BLK - 1) / SCAN_BLK)    // 196
#define GBLK 512                  // gather block threads
#define NPB 85                    // nodes per gather block (85*6 = 510 active threads)
#define NBG ((N_NODES + NPB - 1) / NPB)               // 589 gather blocks
#define CAP 1536                  // LDS entry buffer (int2) per tile (12 KB)
#define R1_ROWS 24
#define R1_BLOCKS ((NBG + R1_ROWS - 1) / R1_ROWS)     // 25
#define SC_PASSES 4
#define SC_WIN ((N_NODES + SC_PASSES - 1) / SC_PASSES)   // 12500 nodes per window
#define F8_SCALE 16.0f
#define F8_INV   0.0625f

typedef short v8s __attribute__((ext_vector_type(8)));   // 8 bf16 = 4 VGPRs
typedef float v4f __attribute__((ext_vector_type(4)));   // MFMA accumulator
typedef float v2f __attribute__((ext_vector_type(2)));

// ---- bf16 helpers (RNE) ----
__device__ __forceinline__ unsigned short f2bf(float f) {
    unsigned int u = __float_as_uint(f);
    u += 0x7FFFu + ((u >> 16) & 1u);
    return (unsigned short)(u >> 16);
}
__device__ __forceinline__ unsigned int pack2bf(float lo, float hi) {
    return (unsigned int)f2bf(lo) | ((unsigned int)f2bf(hi) << 16);
}

__device__ __forceinline__ float fast_tanh(float x) {
    float ax = fabsf(x);
    float t = __expf(-2.0f * ax);
    float r = (1.0f - t) / (1.0f + t);
    return copysignf(r, x);
}

// fp8 e4m3 (OCP on gfx950): 16 fp8 in a uint4 -> 16 f32 accumulate
__device__ __forceinline__ void accf16(float* a, uint4 v, float f) {
    v2f p0 = __builtin_amdgcn_cvt_pk_f32_fp8(v.x, false);
    v2f p1 = __builtin_amdgcn_cvt_pk_f32_fp8(v.x, true);
    v2f p2 = __builtin_amdgcn_cvt_pk_f32_fp8(v.y, false);
    v2f p3 = __builtin_amdgcn_cvt_pk_f32_fp8(v.y, true);
    v2f p4 = __builtin_amdgcn_cvt_pk_f32_fp8(v.z, false);
    v2f p5 = __builtin_amdgcn_cvt_pk_f32_fp8(v.z, true);
    v2f p6 = __builtin_amdgcn_cvt_pk_f32_fp8(v.w, false);
    v2f p7 = __builtin_amdgcn_cvt_pk_f32_fp8(v.w, true);
    a[0]  += p0.x * f; a[1]  += p0.y * f;
    a[2]  += p1.x * f; a[3]  += p1.y * f;
    a[4]  += p2.x * f; a[5]  += p2.y * f;
    a[6]  += p3.x * f; a[7]  += p3.y * f;
    a[8]  += p4.x * f; a[9]  += p4.y * f;
    a[10] += p5.x * f; a[11] += p5.y * f;
    a[12] += p6.x * f; a[13] += p6.y * f;
    a[14] += p7.x * f; a[15] += p7.y * f;
}

union U4S8 { uint4 u; v8s s; };

// ---------------- counting-sort CSR build (rank captured in count pass) ----------------

__global__ void count_deg(const int* __restrict__ dst, int* __restrict__ deg,
                          int* __restrict__ rank) {
    int e = blockIdx.x * blockDim.x + threadIdx.x;
    if (e < N_EDGES) rank[e] = atomicAdd(&deg[dst[e]], 1);
}

__global__ void deg_partials(const int* __restrict__ deg, float* __restrict__ norm,
                             int* __restrict__ partials) {
    int b = blockIdx.x, t = threadIdx.x;
    int n = b * SCAN_BLK + t;
    int v = 0;
    if (n < N_NODES) {
        v = deg[n];
        norm[n] = rsqrtf(fmaxf((float)v, 1.0f));
    }
    int s = v;
#pragma unroll
    for (int off = 32; off > 0; off >>= 1) s += __shfl_down(s, off, 64);
    __shared__ int ws_[4];
    if ((t & 63) == 0) ws_[t >> 6] = s;
    __syncthreads();
    if (t == 0) partials[b] = ws_[0] + ws_[1] + ws_[2] + ws_[3];
}

// fused: every block LDS-scans the 196 partials, then scans its own deg chunk -> offs
__global__ void make_offsets(const int* __restrict__ deg, const int* __restrict__ partials,
                             int* __restrict__ offs) {
    __shared__ int sm[SCAN_BLK];
    __shared__ int sp[SCAN_BLK];
    int b = blockIdx.x, t = threadIdx.x;
    // scan partials (196 values)
    sp[t] = (t < NBLK) ? partials[t] : 0;
    __syncthreads();
    for (int off = 1; off < SCAN_BLK; off <<= 1) {
        int u = (t >= off) ? sp[t - off] : 0;
        __syncthreads();
        sp[t] += u;
        __syncthreads();
    }
    int ppfx = (b > 0) ? sp[b - 1] : 0;
    // scan own chunk
    int idx = b * SCAN_BLK + t;
    int v = (idx < N_NODES) ? deg[idx] : 0;
    sm[t] = v;
    __syncthreads();
    for (int off = 1; off < SCAN_BLK; off <<= 1) {
        int u = (t >= off) ? sm[t - off] : 0;
        __syncthreads();
        sm[t] += u;
        __syncthreads();
    }
    if (idx < N_NODES) offs[idx] = ppfx + sm[t] - v;
    if (b == 0 && t == 0) offs[N_NODES] = N_EDGES;
}

// atomic-free scatter; dst-windowed passes keep the active write region L2-resident.
// norm[src] is folded into the stored factor (exact: msg always uses feat[s]*norm[s]).
__global__ void scatter_edges(const int* __restrict__ src, const int* __restrict__ dst,
                              const float* __restrict__ factor, const int* __restrict__ rank,
                              const int* __restrict__ offs, const float* __restrict__ norm,
                              int2* __restrict__ entries) {
    int tid0 = blockIdx.x * blockDim.x + threadIdx.x;
    int stride = gridDim.x * blockDim.x;
#pragma unroll 1
    for (int pass = 0; pass < SC_PASSES; ++pass) {
        int lo = pass * SC_WIN;
        int hi = min(lo + SC_WIN, N_NODES);
#pragma unroll 1
        for (int e = tid0; e < N_EDGES; e += stride) {
            int d = dst[e];
            if (d >= lo && d < hi) {
                int s = src[e];
                int pos = offs[d] + rank[e];
                float f = factor[e] * norm[s];
                entries[pos] = make_int2(s, __float_as_int(f));
            }
        }
    }
}

// ---------------- W pre-swizzle (both weights in one dispatch) ----------------

__global__ void swizzle_W2(const float* __restrict__ W1, const float* __restrict__ W2,
                           uint4* __restrict__ bsw1, uint4* __restrict__ bsw2) {
    int gidx = blockIdx.x * blockDim.x + threadIdx.x;
    if (gidx >= 2 * 1152) return;
    int w = gidx / 1152, idx = gidx % 1152;
    const float* W = w ? W2 : W1;
    uint4* bsw = w ? bsw2 : bsw1;
    int t = idx >> 6, lane = idx & 63;
    int kt = t / 6, jt = t % 6;
    int quad = lane >> 4, l16 = lane & 15;
    const float4* wp = (const float4*)(W + (size_t)(jt * 16 + l16) * DIM + kt * 32 + quad * 8);
    float4 w0 = wp[0], w1 = wp[1];
    bsw[idx] = make_uint4(pack2bf(w0.x, w0.y), pack2bf(w0.z, w0.w),
                          pack2bf(w1.x, w1.y), pack2bf(w1.z, w1.w));
}

// ---------------- MFMA GEMM (operand-swapped):  D = W x X^T ----------------
// norm is folded into the gather factor, so: out[n][j] = fp8( (X@W^T + b)[n][j] * 16 )

template <typename T>
__global__ __launch_bounds__(256) void gemm_mfma(const T* __restrict__ X,
                                                 const uint4* __restrict__ bsw,
                                                 const float* __restrict__ bias,
                                                 unsigned char* __restrict__ out) {
    int tid = threadIdx.x;
    int wave = tid >> 6, lane = tid & 63;
    int quad = lane >> 4, l16 = lane & 15;
    int n0 = blockIdx.x * 64 + wave * 16;
    int node = n0 + l16;
    int rowc = min(node, N_NODES - 1);

    uint4 bfr[18];
#pragma unroll
    for (int t = 0; t < 18; ++t) bfr[t] = bsw[t * 64 + lane];

    v4f acc[6];
#pragma unroll
    for (int jt = 0; jt < 6; ++jt) acc[jt] = (v4f)(0.0f);

#pragma unroll
    for (int kt = 0; kt < 3; ++kt) {
        U4S8 x;
        if constexpr (std::is_same_v<T, float>) {
            const float4* xp = (const float4*)(X + (size_t)rowc * DIM + kt * 32 + quad * 8);
            float4 x0 = xp[0], x1 = xp[1];
            x.u = make_uint4(pack2bf(x0.x, x0.y), pack2bf(x0.z, x0.w),
                             pack2bf(x1.x, x1.y), pack2bf(x1.z, x1.w));
        } else {
            x.u = *(const uint4*)(X + (size_t)rowc * DIM + kt * 32 + quad * 8);
        }
#pragma unroll
        for (int jt = 0; jt < 6; ++jt) {
            U4S8 w; w.u = bfr[kt * 6 + jt];
            acc[jt] = __builtin_amdgcn_mfma_f32_16x16x32_bf16(w.s, x.s, acc[jt], 0, 0, 0);
        }
    }

    if (node < N_NODES) {
#pragma unroll
        for (int jt = 0; jt < 6; ++jt) {
            float4 bj = *(const float4*)(bias + jt * 16 + quad * 4);
            float v0 = (acc[jt][0] + bj.x) * F8_SCALE;
            float v1 = (acc[jt][1] + bj.y) * F8_SCALE;
            float v2 = (acc[jt][2] + bj.z) * F8_SCALE;
            float v3 = (acc[jt][3] + bj.w) * F8_SCALE;
            unsigned int w = (unsigned int)__builtin_amdgcn_cvt_pk_fp8_f32(v0, v1, 0, false);
            w = (unsigned int)__builtin_amdgcn_cvt_pk_fp8_f32(v2, v3, (int)w, true);
            *(unsigned int*)(out + (size_t)node * DIM + jt * 16 + quad * 4) = w;
        }
    }
}

// ---------------- gather aggregation: 6 lanes x 16B per fp8 row ----------------

template <bool POOL>
__global__ __launch_bounds__(GBLK) void gather_agg_f8(
        const unsigned char* __restrict__ feat,
        const int* __restrict__ offs,
        const int2* __restrict__ entries,
        unsigned short* __restrict__ out,
        float* __restrict__ partials) {
    __shared__ int2 ents[CAP];       // 12 KB
    __shared__ float pool[DIM];
    __shared__ int sh_base, sh_cnt;
    int tid = threadIdx.x;
    int n0 = blockIdx.x * NPB;
    int n1 = min(n0 + NPB, N_NODES);
    if (POOL && tid < DIM) pool[tid] = 0.f;
    if (tid == 0) { sh_base = offs[n0]; sh_cnt = offs[n1] - sh_base; }
    __syncthreads();
    int base = sh_base, cnt = sh_cnt;

    int nl = tid / BCH;
    int c  = tid - nl * BCH;      // 0..5 -> 16 fp8 dims each
    int n  = n0 + nl;
    bool active = (tid < NPB * BCH) && (n < N_NODES);
    int lb = 0, le = 0;
    if (active) { lb = offs[n] - base; le = offs[n + 1] - base; }

    float a[16];
#pragma unroll
    for (int i = 0; i < 16; ++i) a[i] = 0.f;

    for (int tb = 0; tb < cnt; tb += CAP) {
        int tcnt = min(cnt - tb, CAP);
        if (tb) __syncthreads();
        for (int i = tid; i < tcnt; i += GBLK) {
            long long raw = __builtin_nontemporal_load((const long long*)(entries + base + tb + i));
            ents[i] = *(int2*)&raw;
        }
        __syncthreads();
        int s = max(lb - tb, 0), e = min(le - tb, tcnt);
        int p = s;
        // 4 independent 16B gathers in flight
        for (; p + 3 < e; p += 4) {
            int2 q0 = ents[p + 0], q1 = ents[p + 1], q2 = ents[p + 2], q3 = ents[p + 3];
            uint4 v0 = *((const uint4*)(feat + (size_t)q0.x * DIM) + c);
            uint4 v1 = *((const uint4*)(feat + (size_t)q1.x * DIM) + c);
            uint4 v2 = *((const uint4*)(feat + (size_t)q2.x * DIM) + c);
            uint4 v3 = *((const uint4*)(feat + (size_t)q3.x * DIM) + c);
            accf16(a, v0, __int_as_float(q0.y));
            accf16(a, v1, __int_as_float(q1.y));
            accf16(a, v2, __int_as_float(q2.y));
            accf16(a, v3, __int_as_float(q3.y));
        }
        for (; p < e; ++p) {
            int2 q0 = ents[p];
            uint4 v0 = *((const uint4*)(feat + (size_t)q0.x * DIM) + c);
            accf16(a, v0, __int_as_float(q0.y));
        }
    }

#pragma unroll
    for (int i = 0; i < 16; ++i) a[i] = fast_tanh(a[i] * F8_INV);
    if (!POOL) {
        if (active) {
            uint4 o0, o1;
            o0.x = pack2bf(a[0], a[1]);   o0.y = pack2bf(a[2], a[3]);
            o0.z = pack2bf(a[4], a[5]);   o0.w = pack2bf(a[6], a[7]);
            o1.x = pack2bf(a[8], a[9]);   o1.y = pack2bf(a[10], a[11]);
            o1.z = pack2bf(a[12], a[13]); o1.w = pack2bf(a[14], a[15]);
            uint4* op = (uint4*)out + (size_t)n * 12 + c * 2;
            op[0] = o0;
            op[1] = o1;
        }
    } else {
        if (active) {
#pragma unroll
            for (int i = 0; i < 16; ++i) atomicAdd(&pool[c * 16 + i], a[i]);
        }
        __syncthreads();
        if (tid < DIM) partials[(size_t)blockIdx.x * DIM + tid] = pool[tid];
    }
}

// ---------------- two-stage pooled reduce ----------------

__global__ void reduce_stage1(const float* __restrict__ poolpart, float* __restrict__ stage1) {
    __shared__ float pool[DIM];
    int b = blockIdx.x, t = threadIdx.x;
    if (t < DIM) pool[t] = 0.f;
    __syncthreads();
    const int base = b * R1_ROWS * DIM;
    float loc = 0.f;
    int lastc = -1;
    for (int i = t; i < R1_ROWS * DIM; i += 256) {
        int gi = base + i;
        if (gi < NBG * DIM) {
            int col = i % DIM;
            if (col != lastc) {
                if (lastc >= 0) atomicAdd(&pool[lastc], loc);
                lastc = col; loc = 0.f;
            }
            loc += poolpart[gi];
        }
    }
    if (lastc >= 0) atomicAdd(&pool[lastc], loc);
    __syncthreads();
    if (t < DIM) stage1[b * DIM + t] = pool[t];
}

__global__ void reduce_stage2(const float* __restrict__ stage1, float* __restrict__ out) {
    __shared__ float sm[960];
    int t = threadIdx.x;
    int col = t % DIM, slice = t / DIM;
    float s = 0.f;
    for (int k = slice; k < R1_BLOCKS; k += 10) s += stage1[k * DIM + col];
    sm[t] = s;
    __syncthreads();
    if (t < DIM) {
        float tot = 0.f;
#pragma unroll
        for (int i = 0; i < 10; ++i) tot += sm[i * DIM + t];
        out[t] = tanhf(tot * (1.0f / N_NODES));
    }
}

// ---------------- launch ----------------

extern "C" void kernel_launch(void* const* d_in, const int* in_sizes, int n_in,
                              void* d_out, int out_size, void* d_ws, size_t ws_size,
                              hipStream_t stream) {
    const float* inputs = (const float*)d_in[0];
    const float* W1     = (const float*)d_in[1];
    const float* b1     = (const float*)d_in[2];
    const float* W2     = (const float*)d_in[3];
    const float* b2     = (const float*)d_in[4];
    const float* factor = (const float*)d_in[5];
    const int*   src    = (const int*)d_in[6];
    const int*   dst    = (const int*)d_in[7];
    float* out = (float*)d_out;

    char* ws = (char*)d_ws;
    int*            deg      = (int*)(ws + 0);              // 200 KB
    int*            rank     = (int*)(ws + 262144);         // 3.2 MB
    int*            offs     = (int*)(ws + 3670016);        // 200 KB (+1)
    float*          norm     = (float*)(ws + 3932160);      // 200 KB
    int*            partials = (int*)(ws + 4194304);        // 1 KB
    int2*           entries  = (int2*)(ws + 4456448);       // 6.4 MB
    unsigned char*  bufA     = (unsigned char*)(ws + 11534336);   // 4.8 MB fp8 feat
    unsigned short* bufB     = (unsigned short*)(ws + 16777216);  // 9.6 MB bf16 h1
    float*          poolpart = (float*)(ws + 26738688);     // 226 KB (NBG x 96)
    float*          stage1   = (float*)(ws + 27787264);     // 9.6 KB
    uint4*          bsw1     = (uint4*)(ws + 27836416);     // 18 KB W1 fragments
    uint4*          bsw2     = (uint4*)(ws + 27856896);     // 18 KB W2 fragments

    // W fragment pre-swizzle (one dispatch, independent of CSR build)
    swizzle_W2<<<9, 256, 0, stream>>>(W1, W2, bsw1, bsw2);

    // counting-sort CSR build (rank captured during count; scatter is atomic-free)
    hipMemsetAsync(deg, 0, N_NODES * sizeof(int), stream);
    count_deg<<<(N_EDGES + 255) / 256, 256, 0, stream>>>(dst, deg, rank);
    deg_partials<<<NBLK, SCAN_BLK, 0, stream>>>(deg, norm, partials);
    make_offsets<<<NBLK, SCAN_BLK, 0, stream>>>(deg, partials, offs);
    scatter_edges<<<2048, 256, 0, stream>>>(src, dst, factor, rank, offs, norm, entries);

    const int GEMM_BLOCKS = (N_NODES + 63) / 64;   // 782

    // layer 1: feat1 (fp8, un-normed) -> gather (factor*norm folded, +tanh) -> h1 (bf16)
    gemm_mfma<float><<<GEMM_BLOCKS, 256, 0, stream>>>(inputs, bsw1, b1, bufA);
    gather_agg_f8<false><<<NBG, GBLK, 0, stream>>>(bufA, offs, entries, bufB, nullptr);

    // layer 2: feat2 (fp8) -> gather (+tanh) -> per-block pool partials
    gemm_mfma<unsigned short><<<GEMM_BLOCKS, 256, 0, stream>>>(bufB, bsw2, b2, bufA);
    gather_agg_f8<true><<<NBG, GBLK, 0, stream>>>(bufA, offs, entries, nullptr, poolpart);

    // two-stage pooled reduce -> out
    reduce_stage1<<<R1_BLOCKS, 256, 0, stream>>>(poolpart, stage1);
    reduce_stage2<<<1, 960, 0, stream>>>(stage1, out);
}

// Round 10
// 224.157 us; speedup vs baseline: 1.0460x; 1.0460x over previous
//
#include <hip/hip_runtime.h>
#include <math.h>
#include <type_traits>

#define N_NODES 50000
#define N_EDGES 800000
#define DIM 96
#define BCH 12                    // 8-byte fp8 chunks per 96B row
#define SCAN_BLK 256
#define NBLK ((N_NODES + SCAN_BLK - 1) / SCAN_BLK)    // 196
#define GBLK 512                  // gather block threads
#define NPB 42                    // nodes per gather block (42*12 = 504 active threads)
#define NBG ((N_NODES + NPB - 1) / NPB)               // 1191 gather blocks
#define CAP 768                   // LDS entry buffer (int2) per tile
#define R1_ROWS 24
#define R1_BLOCKS ((NBG + R1_ROWS - 1) / R1_ROWS)     // 50
#define SC_PASSES 4
#define SC_WIN ((N_NODES + SC_PASSES - 1) / SC_PASSES)   // 12500 nodes per window
#define F8_SCALE 16.0f
#define F8_INV   0.0625f
#define TILE_SH 104               // padded shorts per h1 LDS row

typedef short v8s __attribute__((ext_vector_type(8)));   // 8 bf16 = 4 VGPRs
typedef float v4f __attribute__((ext_vector_type(4)));   // MFMA accumulator
typedef float v2f __attribute__((ext_vector_type(2)));

// ---- bf16 helpers (RNE) ----
__device__ __forceinline__ unsigned short f2bf(float f) {
    unsigned int u = __float_as_uint(f);
    u += 0x7FFFu + ((u >> 16) & 1u);
    return (unsigned short)(u >> 16);
}
__device__ __forceinline__ unsigned int pack2bf(float lo, float hi) {
    return (unsigned int)f2bf(lo) | ((unsigned int)f2bf(hi) << 16);
}

__device__ __forceinline__ float fast_tanh(float x) {
    float ax = fabsf(x);
    float t = __expf(-2.0f * ax);
    float r = (1.0f - t) / (1.0f + t);
    return copysignf(r, x);
}

// fp8 e4m3 (OCP on gfx950): 8 fp8 in a uint2 -> 8 f32 accumulate
__device__ __forceinline__ void accf8(float* a, uint2 v, float f) {
    v2f p0 = __builtin_amdgcn_cvt_pk_f32_fp8(v.x, false);
    v2f p1 = __builtin_amdgcn_cvt_pk_f32_fp8(v.x, true);
    v2f p2 = __builtin_amdgcn_cvt_pk_f32_fp8(v.y, false);
    v2f p3 = __builtin_amdgcn_cvt_pk_f32_fp8(v.y, true);
    a[0] += p0.x * f; a[1] += p0.y * f;
    a[2] += p1.x * f; a[3] += p1.y * f;
    a[4] += p2.x * f; a[5] += p2.y * f;
    a[6] += p3.x * f; a[7] += p3.y * f;
}

union U4S8 { uint4 u; v8s s; };

// ---------------- counting-sort CSR build (rank captured in count pass) ----------------

__global__ void count_deg(const int* __restrict__ dst, int* __restrict__ deg,
                          int* __restrict__ rank) {
    int e = blockIdx.x * blockDim.x + threadIdx.x;
    if (e < N_EDGES) rank[e] = atomicAdd(&deg[dst[e]], 1);
}

__global__ void deg_partials(const int* __restrict__ deg, float* __restrict__ norm,
                             int* __restrict__ partials) {
    int b = blockIdx.x, t = threadIdx.x;
    int n = b * SCAN_BLK + t;
    int v = 0;
    if (n < N_NODES) {
        v = deg[n];
        norm[n] = rsqrtf(fmaxf((float)v, 1.0f));
    }
    int s = v;
#pragma unroll
    for (int off = 32; off > 0; off >>= 1) s += __shfl_down(s, off, 64);
    __shared__ int ws_[4];
    if ((t & 63) == 0) ws_[t >> 6] = s;
    __syncthreads();
    if (t == 0) partials[b] = ws_[0] + ws_[1] + ws_[2] + ws_[3];
}

__global__ void scan_partials(const int* __restrict__ partials, int* __restrict__ pprefix) {
    __shared__ int sm[SCAN_BLK];
    int t = threadIdx.x;
    int v = (t < NBLK) ? partials[t] : 0;
    sm[t] = v;
    __syncthreads();
    for (int off = 1; off < SCAN_BLK; off <<= 1) {
        int u = (t >= off) ? sm[t - off] : 0;
        __syncthreads();
        sm[t] += u;
        __syncthreads();
    }
    if (t < NBLK) pprefix[t] = sm[t] - v;
}

__global__ void make_offsets(const int* __restrict__ deg, const int* __restrict__ pprefix,
                             int* __restrict__ offs) {
    __shared__ int sm[SCAN_BLK];
    int b = blockIdx.x, t = threadIdx.x;
    int idx = b * SCAN_BLK + t;
    int v = (idx < N_NODES) ? deg[idx] : 0;
    sm[t] = v;
    __syncthreads();
    for (int off = 1; off < SCAN_BLK; off <<= 1) {
        int u = (t >= off) ? sm[t - off] : 0;
        __syncthreads();
        sm[t] += u;
        __syncthreads();
    }
    if (idx < N_NODES) offs[idx] = pprefix[b] + sm[t] - v;
    if (b == 0 && t == 0) offs[N_NODES] = N_EDGES;
}

// atomic-free scatter; dst-windowed passes keep the active write region L2-resident
__global__ void scatter_edges(const int* __restrict__ src, const int* __restrict__ dst,
                              const float* __restrict__ factor, const int* __restrict__ rank,
                              const int* __restrict__ offs, int2* __restrict__ entries) {
    int tid0 = blockIdx.x * blockDim.x + threadIdx.x;
    int stride = gridDim.x * blockDim.x;
#pragma unroll 1
    for (int pass = 0; pass < SC_PASSES; ++pass) {
        int lo = pass * SC_WIN;
        int hi = min(lo + SC_WIN, N_NODES);
#pragma unroll 1
        for (int e = tid0; e < N_EDGES; e += stride) {
            int d = dst[e];
            if (d >= lo && d < hi) {
                int pos = offs[d] + rank[e];
                entries[pos] = make_int2(src[e], __float_as_int(factor[e]));
            }
        }
    }
}

// ---------------- W pre-swizzle: k-contiguous fragments for mfma_f32_16x16x32_bf16 ----

__global__ void swizzle_W(const float* __restrict__ W, uint4* __restrict__ bsw) {
    int idx = blockIdx.x * blockDim.x + threadIdx.x;
    if (idx >= 18 * 64) return;
    int t = idx >> 6, lane = idx & 63;
    int kt = t / 6, jt = t % 6;
    int quad = lane >> 4, l16 = lane & 15;
    const float4* wp = (const float4*)(W + (size_t)(jt * 16 + l16) * DIM + kt * 32 + quad * 8);
    float4 w0 = wp[0], w1 = wp[1];
    bsw[idx] = make_uint4(pack2bf(w0.x, w0.y), pack2bf(w0.z, w0.w),
                          pack2bf(w1.x, w1.y), pack2bf(w1.z, w1.w));
}

// ---------------- MFMA GEMM (operand-swapped):  D = W x X^T ----------------
// D col = node (lane&15), D row = feature dim j = jt*16 + quad*4 + r.
// out[n][j] = fp8( (X@W^T + b)[n][j] * norm[n] * 16 )

template <typename T>
__global__ __launch_bounds__(256) void gemm_mfma(const T* __restrict__ X,
                                                 const uint4* __restrict__ bsw,
                                                 const float* __restrict__ bias,
                                                 const float* __restrict__ norm,
                                                 unsigned char* __restrict__ out) {
    int tid = threadIdx.x;
    int wave = tid >> 6, lane = tid & 63;
    int quad = lane >> 4, l16 = lane & 15;
    int n0 = blockIdx.x * 64 + wave * 16;
    int node = n0 + l16;
    int rowc = min(node, N_NODES - 1);

    uint4 bfr[18];
#pragma unroll
    for (int t = 0; t < 18; ++t) bfr[t] = bsw[t * 64 + lane];

    v4f acc[6];
#pragma unroll
    for (int jt = 0; jt < 6; ++jt) acc[jt] = (v4f)(0.0f);

#pragma unroll
    for (int kt = 0; kt < 3; ++kt) {
        U4S8 x;
        if constexpr (std::is_same_v<T, float>) {
            const float4* xp = (const float4*)(X + (size_t)rowc * DIM + kt * 32 + quad * 8);
            float4 x0 = xp[0], x1 = xp[1];
            x.u = make_uint4(pack2bf(x0.x, x0.y), pack2bf(x0.z, x0.w),
                             pack2bf(x1.x, x1.y), pack2bf(x1.z, x1.w));
        } else {
            x.u = *(const uint4*)(X + (size_t)rowc * DIM + kt * 32 + quad * 8);
        }
#pragma unroll
        for (int jt = 0; jt < 6; ++jt) {
            U4S8 w; w.u = bfr[kt * 6 + jt];
            acc[jt] = __builtin_amdgcn_mfma_f32_16x16x32_bf16(w.s, x.s, acc[jt], 0, 0, 0);
        }
    }

    if (node < N_NODES) {
        float nm = norm[node] * F8_SCALE;
#pragma unroll
        for (int jt = 0; jt < 6; ++jt) {
            float4 bj = *(const float4*)(bias + jt * 16 + quad * 4);
            float v0 = (acc[jt][0] + bj.x) * nm;
            float v1 = (acc[jt][1] + bj.y) * nm;
            float v2 = (acc[jt][2] + bj.z) * nm;
            float v3 = (acc[jt][3] + bj.w) * nm;
            unsigned int w = (unsigned int)__builtin_amdgcn_cvt_pk_fp8_f32(v0, v1, 0, false);
            w = (unsigned int)__builtin_amdgcn_cvt_pk_fp8_f32(v2, v3, (int)w, true);
            *(unsigned int*)(out + (size_t)node * DIM + jt * 16 + quad * 4) = w;
        }
    }
}

// ---------------- fused gather-1 + layer-2 GEMM ----------------
// Phase 1 (all 512 threads): gather feat1[src]*factor, tanh -> h1 (bf16) into LDS.
// Phase 2 (waves 0..2): B-fragments from LDS, A = W2 fragments, MFMA,
// epilogue (+b2, *norm, *16) -> fp8 feat2 directly. gemm2 dispatch eliminated.

__global__ __launch_bounds__(GBLK) void gather_fuse(
        const unsigned char* __restrict__ feat,
        const int* __restrict__ offs,
        const int2* __restrict__ entries,
        const uint4* __restrict__ bsw2,
        const float* __restrict__ bias2,
        const float* __restrict__ norm,
        unsigned char* __restrict__ feat2) {
    __shared__ int2 ents[CAP];                            // 6 KB
    __shared__ __align__(16) unsigned short h1s[48 * TILE_SH];  // 9.98 KB
    __shared__ int sh_base, sh_cnt;
    int tid = threadIdx.x;
    // zero h1 tile (rows beyond this block's nodes must be zero for the MFMA)
    for (int i = tid; i < 48 * TILE_SH / 2; i += GBLK) ((unsigned int*)h1s)[i] = 0u;
    int n0 = blockIdx.x * NPB;
    int n1 = min(n0 + NPB, N_NODES);
    if (tid == 0) { sh_base = offs[n0]; sh_cnt = offs[n1] - sh_base; }
    __syncthreads();
    int base = sh_base, cnt = sh_cnt;

    int nl = tid / BCH;
    int c  = tid - nl * BCH;
    int n  = n0 + nl;
    bool active = (tid < NPB * BCH) && (n < N_NODES);
    int lb = 0, le = 0;
    if (active) { lb = offs[n] - base; le = offs[n + 1] - base; }

    float a0[8], a1[8];
#pragma unroll
    for (int i = 0; i < 8; ++i) { a0[i] = 0.f; a1[i] = 0.f; }

    for (int tb = 0; tb < cnt; tb += CAP) {
        int tcnt = min(cnt - tb, CAP);
        if (tb) __syncthreads();
        for (int i = tid; i < tcnt; i += GBLK) ents[i] = entries[base + tb + i];
        __syncthreads();
        int s = max(lb - tb, 0), e = min(le - tb, tcnt);
        int p = s;
        for (; p + 7 < e; p += 8) {
            int2 q0 = ents[p + 0], q1 = ents[p + 1], q2 = ents[p + 2], q3 = ents[p + 3];
            int2 q4 = ents[p + 4], q5 = ents[p + 5], q6 = ents[p + 6], q7 = ents[p + 7];
            uint2 v0 = *((const uint2*)(feat + (size_t)q0.x * DIM) + c);
            uint2 v1 = *((const uint2*)(feat + (size_t)q1.x * DIM) + c);
            uint2 v2 = *((const uint2*)(feat + (size_t)q2.x * DIM) + c);
            uint2 v3 = *((const uint2*)(feat + (size_t)q3.x * DIM) + c);
            uint2 v4 = *((const uint2*)(feat + (size_t)q4.x * DIM) + c);
            uint2 v5 = *((const uint2*)(feat + (size_t)q5.x * DIM) + c);
            uint2 v6 = *((const uint2*)(feat + (size_t)q6.x * DIM) + c);
            uint2 v7 = *((const uint2*)(feat + (size_t)q7.x * DIM) + c);
            accf8(a0, v0, __int_as_float(q0.y));
            accf8(a1, v1, __int_as_float(q1.y));
            accf8(a0, v2, __int_as_float(q2.y));
            accf8(a1, v3, __int_as_float(q3.y));
            accf8(a0, v4, __int_as_float(q4.y));
            accf8(a1, v5, __int_as_float(q5.y));
            accf8(a0, v6, __int_as_float(q6.y));
            accf8(a1, v7, __int_as_float(q7.y));
        }
        for (; p + 3 < e; p += 4) {
            int2 q0 = ents[p], q1 = ents[p + 1], q2 = ents[p + 2], q3 = ents[p + 3];
            uint2 v0 = *((const uint2*)(feat + (size_t)q0.x * DIM) + c);
            uint2 v1 = *((const uint2*)(feat + (size_t)q1.x * DIM) + c);
            uint2 v2 = *((const uint2*)(feat + (size_t)q2.x * DIM) + c);
            uint2 v3 = *((const uint2*)(feat + (size_t)q3.x * DIM) + c);
            accf8(a0, v0, __int_as_float(q0.y));
            accf8(a1, v1, __int_as_float(q1.y));
            accf8(a0, v2, __int_as_float(q2.y));
            accf8(a1, v3, __int_as_float(q3.y));
        }
        for (; p < e; ++p) {
            int2 q0 = ents[p];
            uint2 v0 = *((const uint2*)(feat + (size_t)q0.x * DIM) + c);
            accf8(a0, v0, __int_as_float(q0.y));
        }
    }

    // tanh -> bf16 -> LDS h1 tile (row nl, dims c*8..c*8+7)
    if (active) {
#pragma unroll
        for (int i = 0; i < 8; ++i) a0[i] = fast_tanh((a0[i] + a1[i]) * F8_INV);
        uint4 o;
        o.x = pack2bf(a0[0], a0[1]);
        o.y = pack2bf(a0[2], a0[3]);
        o.z = pack2bf(a0[4], a0[5]);
        o.w = pack2bf(a0[6], a0[7]);
        *(uint4*)&h1s[nl * TILE_SH + c * 8] = o;
    }
    __syncthreads();

    // ---- layer-2 GEMM on the LDS tile: waves 0..2, one 16-node tile each ----
    int wave = tid >> 6, lane = tid & 63;
    if (wave < 3) {
        int quad = lane >> 4, l16 = lane & 15;
        uint4 bfr[18];
#pragma unroll
        for (int t = 0; t < 18; ++t) bfr[t] = bsw2[t * 64 + lane];
        v4f acc[6];
#pragma unroll
        for (int jt = 0; jt < 6; ++jt) acc[jt] = (v4f)(0.0f);
#pragma unroll
        for (int kt = 0; kt < 3; ++kt) {
            U4S8 x;
            x.u = *(const uint4*)&h1s[(wave * 16 + l16) * TILE_SH + kt * 32 + quad * 8];
#pragma unroll
            for (int jt = 0; jt < 6; ++jt) {
                U4S8 w; w.u = bfr[kt * 6 + jt];
                acc[jt] = __builtin_amdgcn_mfma_f32_16x16x32_bf16(w.s, x.s, acc[jt], 0, 0, 0);
            }
        }
        int local = wave * 16 + l16;
        int node = n0 + local;
        if (local < n1 - n0) {
            float nm = norm[node] * F8_SCALE;
#pragma unroll
            for (int jt = 0; jt < 6; ++jt) {
                float4 bj = *(const float4*)(bias2 + jt * 16 + quad * 4);
                float v0 = (acc[jt][0] + bj.x) * nm;
                float v1 = (acc[jt][1] + bj.y) * nm;
                float v2 = (acc[jt][2] + bj.z) * nm;
                float v3 = (acc[jt][3] + bj.w) * nm;
                unsigned int w = (unsigned int)__builtin_amdgcn_cvt_pk_fp8_f32(v0, v1, 0, false);
                w = (unsigned int)__builtin_amdgcn_cvt_pk_fp8_f32(v2, v3, (int)w, true);
                *(unsigned int*)(feat2 + (size_t)node * DIM + jt * 16 + quad * 4) = w;
            }
        }
    }
}

// ---------------- gather-2: fp8 rows + tanh + per-block pool partials ----------------

__global__ __launch_bounds__(GBLK) void gather_pool(
        const unsigned char* __restrict__ feat,
        const int* __restrict__ offs,
        const int2* __restrict__ entries,
        float* __restrict__ partials) {
    __shared__ int2 ents[CAP];       // 6 KB
    __shared__ float pool[DIM];
    __shared__ int sh_base, sh_cnt;
    int tid = threadIdx.x;
    int n0 = blockIdx.x * NPB;
    int n1 = min(n0 + NPB, N_NODES);
    if (tid < DIM) pool[tid] = 0.f;
    if (tid == 0) { sh_base = offs[n0]; sh_cnt = offs[n1] - sh_base; }
    __syncthreads();
    int base = sh_base, cnt = sh_cnt;

    int nl = tid / BCH;
    int c  = tid - nl * BCH;
    int n  = n0 + nl;
    bool active = (tid < NPB * BCH) && (n < N_NODES);
    int lb = 0, le = 0;
    if (active) { lb = offs[n] - base; le = offs[n + 1] - base; }

    float a0[8], a1[8];
#pragma unroll
    for (int i = 0; i < 8; ++i) { a0[i] = 0.f; a1[i] = 0.f; }

    for (int tb = 0; tb < cnt; tb += CAP) {
        int tcnt = min(cnt - tb, CAP);
        if (tb) __syncthreads();
        for (int i = tid; i < tcnt; i += GBLK) ents[i] = entries[base + tb + i];
        __syncthreads();
        int s = max(lb - tb, 0), e = min(le - tb, tcnt);
        int p = s;
        for (; p + 7 < e; p += 8) {
            int2 q0 = ents[p + 0], q1 = ents[p + 1], q2 = ents[p + 2], q3 = ents[p + 3];
            int2 q4 = ents[p + 4], q5 = ents[p + 5], q6 = ents[p + 6], q7 = ents[p + 7];
            uint2 v0 = *((const uint2*)(feat + (size_t)q0.x * DIM) + c);
            uint2 v1 = *((const uint2*)(feat + (size_t)q1.x * DIM) + c);
            uint2 v2 = *((const uint2*)(feat + (size_t)q2.x * DIM) + c);
            uint2 v3 = *((const uint2*)(feat + (size_t)q3.x * DIM) + c);
            uint2 v4 = *((const uint2*)(feat + (size_t)q4.x * DIM) + c);
            uint2 v5 = *((const uint2*)(feat + (size_t)q5.x * DIM) + c);
            uint2 v6 = *((const uint2*)(feat + (size_t)q6.x * DIM) + c);
            uint2 v7 = *((const uint2*)(feat + (size_t)q7.x * DIM) + c);
            accf8(a0, v0, __int_as_float(q0.y));
            accf8(a1, v1, __int_as_float(q1.y));
            accf8(a0, v2, __int_as_float(q2.y));
            accf8(a1, v3, __int_as_float(q3.y));
            accf8(a0, v4, __int_as_float(q4.y));
            accf8(a1, v5, __int_as_float(q5.y));
            accf8(a0, v6, __int_as_float(q6.y));
            accf8(a1, v7, __int_as_float(q7.y));
        }
        for (; p + 3 < e; p += 4) {
            int2 q0 = ents[p], q1 = ents[p + 1], q2 = ents[p + 2], q3 = ents[p + 3];
            uint2 v0 = *((const uint2*)(feat + (size_t)q0.x * DIM) + c);
            uint2 v1 = *((const uint2*)(feat + (size_t)q1.x * DIM) + c);
            uint2 v2 = *((const uint2*)(feat + (size_t)q2.x * DIM) + c);
            uint2 v3 = *((const uint2*)(feat + (size_t)q3.x * DIM) + c);
            accf8(a0, v0, __int_as_float(q0.y));
            accf8(a1, v1, __int_as_float(q1.y));
            accf8(a0, v2, __int_as_float(q2.y));
            accf8(a1, v3, __int_as_float(q3.y));
        }
        for (; p < e; ++p) {
            int2 q0 = ents[p];
            uint2 v0 = *((const uint2*)(feat + (size_t)q0.x * DIM) + c);
            accf8(a0, v0, __int_as_float(q0.y));
        }
    }

#pragma unroll
    for (int i = 0; i < 8; ++i) a0[i] = fast_tanh((a0[i] + a1[i]) * F8_INV);
    if (active) {
#pragma unroll
        for (int i = 0; i < 8; ++i) atomicAdd(&pool[c * 8 + i], a0[i]);
    }
    __syncthreads();
    if (tid < DIM) partials[(size_t)blockIdx.x * DIM + tid] = pool[tid];
}

// ---------------- two-stage pooled reduce ----------------

__global__ void reduce_stage1(const float* __restrict__ poolpart, float* __restrict__ stage1) {
    __shared__ float pool[DIM];
    int b = blockIdx.x, t = threadIdx.x;
    if (t < DIM) pool[t] = 0.f;
    __syncthreads();
    const int base = b * R1_ROWS * DIM;
    float loc = 0.f;
    int lastc = -1;
    for (int i = t; i < R1_ROWS * DIM; i += 256) {
        int gi = base + i;
        if (gi < NBG * DIM) {
            int col = i % DIM;
            if (col != lastc) {
                if (lastc >= 0) atomicAdd(&pool[lastc], loc);
                lastc = col; loc = 0.f;
            }
            loc += poolpart[gi];
        }
    }
    if (lastc >= 0) atomicAdd(&pool[lastc], loc);
    __syncthreads();
    if (t < DIM) stage1[b * DIM + t] = pool[t];
}

__global__ void reduce_stage2(const float* __restrict__ stage1, float* __restrict__ out) {
    __shared__ float sm[960];
    int t = threadIdx.x;
    int col = t % DIM, slice = t / DIM;
    float s = 0.f;
    for (int k = slice; k < R1_BLOCKS; k += 10) s += stage1[k * DIM + col];
    sm[t] = s;
    __syncthreads();
    if (t < DIM) {
        float tot = 0.f;
#pragma unroll
        for (int i = 0; i < 10; ++i) tot += sm[i * DIM + t];
        out[t] = tanhf(tot * (1.0f / N_NODES));
    }
}

// ---------------- launch ----------------

extern "C" void kernel_launch(void* const* d_in, const int* in_sizes, int n_in,
                              void* d_out, int out_size, void* d_ws, size_t ws_size,
                              hipStream_t stream) {
    const float* inputs = (const float*)d_in[0];
    const float* W1     = (const float*)d_in[1];
    const float* b1     = (const float*)d_in[2];
    const float* W2     = (const float*)d_in[3];
    const float* b2     = (const float*)d_in[4];
    const float* factor = (const float*)d_in[5];
    const int*   src    = (const int*)d_in[6];
    const int*   dst    = (const int*)d_in[7];
    float* out = (float*)d_out;

    char* ws = (char*)d_ws;
    int*            deg      = (int*)(ws + 0);              // 200 KB
    int*            rank     = (int*)(ws + 262144);         // 3.2 MB
    int*            offs     = (int*)(ws + 3670016);        // 200 KB (+1)
    float*          norm     = (float*)(ws + 3932160);      // 200 KB
    int*            partials = (int*)(ws + 4194304);        // 1 KB
    int*            pprefix  = (int*)(ws + 4196352);        // 1 KB
    int2*           entries  = (int2*)(ws + 4456448);       // 6.4 MB
    unsigned char*  bufA     = (unsigned char*)(ws + 11534336);   // 4.8 MB fp8 feat1
    unsigned char*  bufB     = (unsigned char*)(ws + 16777216);   // 4.8 MB fp8 feat2
    float*          poolpart = (float*)(ws + 26738688);     // 458 KB (NBG x 96)
    float*          stage1   = (float*)(ws + 27787264);     // 19.2 KB
    uint4*          bsw1     = (uint4*)(ws + 27836416);     // 18 KB W1 fragments
    uint4*          bsw2     = (uint4*)(ws + 27856896);     // 18 KB W2 fragments

    // W fragment pre-swizzle (independent of CSR build)
    swizzle_W<<<5, 256, 0, stream>>>(W1, bsw1);
    swizzle_W<<<5, 256, 0, stream>>>(W2, bsw2);

    // counting-sort CSR build (rank captured during count; scatter is atomic-free)
    hipMemsetAsync(deg, 0, N_NODES * sizeof(int), stream);
    count_deg<<<(N_EDGES + 255) / 256, 256, 0, stream>>>(dst, deg, rank);
    deg_partials<<<NBLK, SCAN_BLK, 0, stream>>>(deg, norm, partials);
    scan_partials<<<1, SCAN_BLK, 0, stream>>>(partials, pprefix);
    make_offsets<<<NBLK, SCAN_BLK, 0, stream>>>(deg, pprefix, offs);
    scatter_edges<<<2048, 256, 0, stream>>>(src, dst, factor, rank, offs, entries);

    const int GEMM_BLOCKS = (N_NODES + 63) / 64;   // 782

    // layer 1 GEMM: feat1 (fp8, normed)
    gemm_mfma<float><<<GEMM_BLOCKS, 256, 0, stream>>>(inputs, bsw1, b1, norm, bufA);

    // fused: gather-1 (+tanh) + layer-2 GEMM -> feat2 (fp8) directly
    gather_fuse<<<NBG, GBLK, 0, stream>>>(bufA, offs, entries, bsw2, b2, norm, bufB);

    // gather-2 (+tanh) -> per-block pool partials
    gather_pool<<<NBG, GBLK, 0, stream>>>(bufB, offs, entries, poolpart);

    // two-stage pooled reduce -> out
    reduce_stage1<<<R1_BLOCKS, 256, 0, stream>>>(poolpart, stage1);
    reduce_stage2<<<1, 960, 0, stream>>>(stage1, out);
}